// Round 13
// baseline (189.979 us; speedup 1.0000x reference)
//
#include <hip/hip_runtime.h>
#include <cstdint>
#include <cstddef>

typedef float f32x4 __attribute__((ext_vector_type(4)));
typedef __bf16 bf16x8 __attribute__((ext_vector_type(8)));

#define BB 16
#define SEQ 1024
#define DMODEL 768
#define NHEAD 12
#define HDIM 64
#define MTOT (BB * SEQ)
#define NQKV (3 * DMODEL)
#define NQK (2 * DMODEL)   // natural-layout Q|K row length
// 0.125 (hd^-0.5) * log2(e): QK^T then exp2 == exp(0.125 * qk)
#define QSCALE 0.18033688011112042f

static __device__ __forceinline__ unsigned short f2bf(float f) {
  unsigned int u = __builtin_bit_cast(unsigned int, f);
  u += 0x7fffu + ((u >> 16) & 1u);
  return (unsigned short)(u >> 16);
}

static __device__ __forceinline__ unsigned cvt_pk_bf16(float lo, float hi) {
  unsigned r;
  asm("v_cvt_pk_bf16_f32 %0, %1, %2" : "=v"(r) : "v"(lo), "v"(hi));
  return r;
}

static __device__ __forceinline__ float max3f(float a, float b, float c) {
  return fmaxf(fmaxf(a, b), c);   // clang fuses to v_max3_f32 (T17)
}

static __device__ __forceinline__ void gload_lds16(const void* g, void* l) {
  __builtin_amdgcn_global_load_lds((__attribute__((address_space(1))) void*)g,
                                   (__attribute__((address_space(3))) void*)l,
                                   16, 0, 0);
}

// ---- fused prep: x->bf16 cvt (blocks 0..1023) + both weight transposes ----
__global__ __launch_bounds__(256) void k_prep(
    const float4* __restrict__ x4, ushort4* __restrict__ xb4,
    const float* __restrict__ qkv_w, unsigned short* __restrict__ WqT,
    const float* __restrict__ proj_w, unsigned short* __restrict__ WpT) {
  const int blk = blockIdx.x;
  if (blk < 1024) {
    const int n4 = MTOT * DMODEL / 4;
    const int stride = 1024 * 256;
    for (int i = blk * 256 + threadIdx.x; i < n4; i += stride) {
      float4 v = x4[i];
      ushort4 o;
      o.x = f2bf(v.x); o.y = f2bf(v.y); o.z = f2bf(v.z); o.w = f2bf(v.w);
      xb4[i] = o;
    }
    return;
  }
  __shared__ float tile[32][33];
  const float* in; unsigned short* out; int C, scaleN, bx, by;
  if (blk < 1024 + 1728) {
    const int l = blk - 1024; bx = l % 72; by = l / 72;
    in = qkv_w; out = WqT; C = NQKV; scaleN = DMODEL;
  } else {
    const int l = blk - 2752; bx = l % 24; by = l / 24;
    in = proj_w; out = WpT; C = DMODEL; scaleN = 0;
  }
  const int R = DMODEL;
  const int tx = threadIdx.x & 31, ty = threadIdx.x >> 5;
  const int c0 = bx * 32, r0 = by * 32;
#pragma unroll
  for (int i = 0; i < 4; ++i)
    tile[ty + i * 8][tx] = in[(size_t)(r0 + ty + i * 8) * C + c0 + tx];
  __syncthreads();
#pragma unroll
  for (int i = 0; i < 4; ++i) {
    const int n = c0 + ty + i * 8;  // original column = output row
    float v = tile[tx][ty + i * 8];
    if (n < scaleN) v *= QSCALE;
    out[(size_t)n * R + r0 + tx] = f2bf(v);
  }
}

// ---- GEMM C[M,N] = A[M,K] * Bt[N,K]^T, bf16 in, f32 accum ----
// 128x128 tile, BK=32 DOUBLE-buffered (2 x 16 KB = same 32 KB total -> still
// 4 blocks/CU), ONE __syncthreads per K-tile with ISSUE-EARLY staging: the
// barrier drains loads issued a full compute phase (~16 MFMA + 8 ds_read x 16
// resident waves) earlier, instead of 0 cycles earlier (R12's exposed drain).
// Same totals as R12: 24 barriers, 96 gloads, 192 ds_reads, 384 MFMA per wave.
// Swizzle (rule 21, R5/R6 math, measured-0-conflict): 16B src blk =
// (lane&3)^((lane>>3)&3); read elem offset ^= ((row>>1)&3)*8.
// MODE 0: outF = C + bias. MODE 1: natural Q|K [m][1536] + packed V^T.
template <int MODE>
__global__ __launch_bounds__(256, 4) void k_gemm_bt(
    const unsigned short* __restrict__ A, const unsigned short* __restrict__ Bt,
    int M, int N, int K,
    float* __restrict__ outF, const float* __restrict__ bias,
    unsigned short* __restrict__ QK, unsigned short* __restrict__ Vt) {
  __shared__ __align__(16) unsigned short As[2][128 * 32];  // 8 KB each
  __shared__ __align__(16) unsigned short Bs[2][128 * 32];  // 8 KB each
  const int tid = threadIdx.x;
  const int lane = tid & 63, wid = tid >> 6;
  const int ln15 = lane & 15, lh = lane >> 4;
  const int wr = wid >> 1, wc = wid & 1;
  const int m0 = blockIdx.x * 128, n0 = blockIdx.y * 128;
  f32x4 acc[4][4] = {};
  // staging: 1KB chunk = 16 rows x 64B; lane -> row (lane>>2), phys blk (lane&3);
  // source carries the inverse swizzle: src blk = (lane&3) ^ ((lane>>3)&3)
  const int srow = lane >> 2;
  const int sblk = ((lane & 3) ^ ((lane >> 3) & 3)) * 8;
  // fragment-read swizzle: phys elem = (lh*8) ^ fswz, fswz = ((row>>1)&3)*8
  const int fswz = ((ln15 >> 1) & 3) << 3;
  const int nk = K >> 5;

  auto stage = [&](int kt, int s) {
    const int k0 = kt * 32;
#pragma unroll
    for (int c = 0; c < 2; ++c) {   // A,B: 8 chunks each; wave takes 2+2
      const int ch = wid * 2 + c;
      const int row = ch * 16 + srow;
      gload_lds16(A + (size_t)(m0 + row) * K + k0 + sblk, &As[s][ch * 512]);
      gload_lds16(Bt + (size_t)(n0 + row) * K + k0 + sblk, &Bs[s][ch * 512]);
    }
  };

  stage(0, 0);
  for (int kt = 0; kt < nk; ++kt) {
    const int s = kt & 1;
    __syncthreads();                        // drains stage(kt); frees buf s^1
    if (kt + 1 < nk) stage(kt + 1, s ^ 1);  // issue-early: full phase of cover
    bf16x8 af[4], bfv[4];
#pragma unroll
    for (int mt = 0; mt < 4; ++mt)
      af[mt] = *reinterpret_cast<const bf16x8*>(
          &As[s][(wr * 64 + mt * 16 + ln15) * 32 + ((lh * 8) ^ fswz)]);
#pragma unroll
    for (int nn = 0; nn < 4; ++nn)
      bfv[nn] = *reinterpret_cast<const bf16x8*>(
          &Bs[s][(wc * 64 + nn * 16 + ln15) * 32 + ((lh * 8) ^ fswz)]);
#pragma unroll
    for (int mt = 0; mt < 4; ++mt)
#pragma unroll
      for (int nn = 0; nn < 4; ++nn)
        acc[mt][nn] = __builtin_amdgcn_mfma_f32_16x16x32_bf16(af[mt], bfv[nn], acc[mt][nn], 0, 0, 0);
  }

#pragma unroll
  for (int mt = 0; mt < 4; ++mt) {
#pragma unroll
    for (int nn = 0; nn < 4; ++nn) {
      const int nb = n0 + wc * 64 + nn * 16;
      const int mb = m0 + wr * 64 + mt * 16 + lh * 4;
      if (MODE == 0) {
#pragma unroll
        for (int r = 0; r < 4; ++r)
          outF[(size_t)(mb + r) * N + nb + ln15] = acc[mt][nn][r] + bias[nb + ln15];
      } else if (nb < NQK) {
#pragma unroll
        for (int r = 0; r < 4; ++r)
          QK[(size_t)(mb + r) * NQK + nb + ln15] = f2bf(acc[mt][nn][r]);
      } else {
        const int rr = nb + ln15 - NQK;
        const int h = rr >> 6, d = rr & 63;
        const int b = mb >> 10, nr0 = mb & 1023;
        ushort4 u;
        u.x = f2bf(acc[mt][nn][0]); u.y = f2bf(acc[mt][nn][1]);
        u.z = f2bf(acc[mt][nn][2]); u.w = f2bf(acc[mt][nn][3]);
        *reinterpret_cast<ushort4*>(
            &Vt[(((size_t)b * NHEAD + h) * HDIM + d) * SEQ + nr0]) = u;
      }
    }
  }
}

// ---- fused flash attention, swapped-QK^T, low-VALU softmax (unchanged) ----
__global__ __launch_bounds__(512) void k_attn(
    const unsigned short* __restrict__ QKn, const unsigned short* __restrict__ Vt,
    unsigned short* __restrict__ O) {
  __shared__ __align__(16) unsigned short Ks[2][64 * 64];   // [kpos][d], swizzled
  __shared__ __align__(16) unsigned short Vs[2][64 * 64];   // [d][kpos], swizzled
  __shared__ __align__(16) unsigned short Ps[8][16 * 72];   // per-wave P [q][kpos]
  const int tid = threadIdx.x;
  const int lane = tid & 63, w = tid >> 6;
  const int ln15 = lane & 15, lh = lane >> 4;
  const int o = blockIdx.x;
  const int sid = (o & 7) * 192 + (o >> 3);
  const int qb = sid & 7;
  const int bhid = sid >> 3;
  const int h = bhid % NHEAD;
  const int b = bhid / NHEAD;
  const size_t bh = (size_t)(b * NHEAD + h);
  const unsigned short* Qbase = QKn + (size_t)(b * SEQ + qb * 128 + w * 16) * NQK + h * HDIM;
  const unsigned short* Kbase = QKn + (size_t)(b * SEQ) * NQK + DMODEL + h * HDIM;
  const unsigned short* Vbase = Vt + bh * HDIM * SEQ;

  const int srow = lane >> 3;
  const int sblk = ((lane & 7) ^ srow) * 8;
  const int swz = (ln15 & 7) << 3;

  auto stage = [&](int kb, int s) {
    const int row = w * 8 + srow;
    gload_lds16(Kbase + (size_t)(kb * 64 + row) * NQK + sblk, &Ks[s][w * 512]);
    gload_lds16(Vbase + (size_t)row * SEQ + kb * 64 + sblk, &Vs[s][w * 512]);
  };

  bf16x8 aq[2];
#pragma unroll
  for (int ch = 0; ch < 2; ++ch)
    aq[ch] = *reinterpret_cast<const bf16x8*>(Qbase + (size_t)ln15 * NQK + ch * 32 + lh * 8);

  bf16x8 onesb;
#pragma unroll
  for (int i = 0; i < 8; ++i) onesb[i] = (__bf16)1.0f;

  f32x4 acc[4] = {};
  f32x4 accl = {};          // row-sums via ones-MFMA; elem r <-> q-row lh*4+r
  float mr = 0.f;           // running max (log2 domain)
  f32x4 cinit = {};         // splat(-mr)

  stage(0, 0);
  for (int kb = 0; kb < SEQ / 64; ++kb) {
    const int s = kb & 1;
    __syncthreads();
    if (kb + 1 < SEQ / 64) stage(kb + 1, s ^ 1);

    // S^T = K Q^T with C = -mr  ->  sv holds (qk - mr)
    f32x4 sv[4];
#pragma unroll
    for (int t = 0; t < 4; ++t) sv[t] = cinit;
    __builtin_amdgcn_s_setprio(1);
#pragma unroll
    for (int t = 0; t < 4; ++t) {
#pragma unroll
      for (int ch = 0; ch < 2; ++ch) {
        bf16x8 bk = *reinterpret_cast<const bf16x8*>(
            &Ks[s][(t * 16 + ln15) * 64 + ((ch * 32 + lh * 8) ^ swz)]);
        sv[t] = __builtin_amdgcn_mfma_f32_16x16x32_bf16(bk, aq[ch], sv[t], 0, 0, 0);
      }
    }
    __builtin_amdgcn_s_setprio(0);

    // in-lane partial max: balanced max3 tree (7 ops, depth 3)
    float pm;
    {
      const float g0 = max3f(sv[0][0], sv[0][1], sv[0][2]);
      const float g1 = max3f(sv[0][3], sv[1][0], sv[1][1]);
      const float g2 = max3f(sv[1][2], sv[1][3], sv[2][0]);
      const float g3 = max3f(sv[2][1], sv[2][2], sv[2][3]);
      const float g4 = max3f(sv[3][0], sv[3][1], sv[3][2]);
      pm = fmaxf(max3f(g0, g1, g2), max3f(g3, g4, sv[3][3]));
    }
    // defer-max: rescale only when some row grew past +8 (P bounded by 2^8)
    if (__any(pm > 8.f)) {
      float bmf = pm;
      bmf = fmaxf(bmf, __shfl_xor(bmf, 16));
      bmf = fmaxf(bmf, __shfl_xor(bmf, 32));          // full-row (qk - mr) max
      const float delta = fmaxf(bmf, 0.f);
      const float al = __builtin_amdgcn_exp2f(-delta);
#pragma unroll
      for (int t = 0; t < 4; ++t)
#pragma unroll
        for (int r = 0; r < 4; ++r) sv[t][r] -= delta;
      mr += delta;
      cinit[0] = -mr; cinit[1] = -mr; cinit[2] = -mr; cinit[3] = -mr;
      float alq[4];
#pragma unroll
      for (int r = 0; r < 4; ++r) alq[r] = __shfl(al, lh * 4 + r);
#pragma unroll
      for (int dt = 0; dt < 4; ++dt)
#pragma unroll
        for (int r = 0; r < 4; ++r) acc[dt][r] *= alq[r];
#pragma unroll
      for (int r = 0; r < 4; ++r) accl[r] *= alq[r];
    }

#pragma unroll
    for (int t = 0; t < 4; ++t)
#pragma unroll
      for (int r = 0; r < 4; ++r) sv[t][r] = __builtin_amdgcn_exp2f(sv[t][r]);

    // pack P -> LDS (A-fragment redistribution)
#pragma unroll
    for (int t = 0; t < 4; ++t) {
      uint2 u;
      u.x = cvt_pk_bf16(sv[t][0], sv[t][1]);
      u.y = cvt_pk_bf16(sv[t][2], sv[t][3]);
      *reinterpret_cast<uint2*>(&Ps[w][ln15 * 72 + t * 16 + lh * 4]) = u;
    }

    bf16x8 ap[2];
#pragma unroll
    for (int ch = 0; ch < 2; ++ch)
      ap[ch] = *reinterpret_cast<const bf16x8*>(&Ps[w][ln15 * 72 + ch * 32 + lh * 8]);
    __builtin_amdgcn_s_setprio(1);
#pragma unroll
    for (int ch = 0; ch < 2; ++ch)   // row-sum MFMA
      accl = __builtin_amdgcn_mfma_f32_16x16x32_bf16(ap[ch], onesb, accl, 0, 0, 0);
#pragma unroll
    for (int dt = 0; dt < 4; ++dt) {
#pragma unroll
      for (int ch = 0; ch < 2; ++ch) {
        bf16x8 bv = *reinterpret_cast<const bf16x8*>(
            &Vs[s][(dt * 16 + ln15) * 64 + ((ch * 32 + lh * 8) ^ swz)]);
        acc[dt] = __builtin_amdgcn_mfma_f32_16x16x32_bf16(ap[ch], bv, acc[dt], 0, 0, 0);
      }
    }
    __builtin_amdgcn_s_setprio(0);
  }

  const int qrow = qb * 128 + w * 16 + lh * 4;
#pragma unroll
  for (int dt = 0; dt < 4; ++dt)
#pragma unroll
    for (int r = 0; r < 4; ++r)
      O[((size_t)b * SEQ + qrow + r) * DMODEL + h * 64 + dt * 16 + ln15] =
          f2bf(acc[dt][r] / accl[r]);
}

extern "C" void kernel_launch(void* const* d_in, const int* in_sizes, int n_in,
                              void* d_out, int out_size, void* d_ws, size_t ws_size,
                              hipStream_t stream) {
  const float* x      = (const float*)d_in[0];
  const float* qkv_w  = (const float*)d_in[1];
  const float* proj_w = (const float*)d_in[2];
  const float* proj_b = (const float*)d_in[3];
  float* out = (float*)d_out;

  char* ws = (char*)d_ws;
  const size_t SZ_XB   = (size_t)MTOT * DMODEL * 2;   // x bf16; reused as attn-out bf16
  const size_t SZ_WQT  = (size_t)NQKV * DMODEL * 2;
  const size_t SZ_WPT  = (size_t)DMODEL * DMODEL * 2;
  const size_t SZ_QK   = (size_t)MTOT * NQK * 2;      // natural Q|K [m][1536]
  const size_t SZ_VT   = (size_t)BB * NHEAD * HDIM * SEQ * 2;
  unsigned short* Xb   = (unsigned short*)ws;
  unsigned short* WqT  = (unsigned short*)(ws + SZ_XB);
  unsigned short* WpT  = (unsigned short*)(ws + SZ_XB + SZ_WQT);
  unsigned short* QKn  = (unsigned short*)(ws + SZ_XB + SZ_WQT + SZ_WPT);
  unsigned short* Vt   = (unsigned short*)(ws + SZ_XB + SZ_WQT + SZ_WPT + SZ_QK);
  if (ws_size < SZ_XB + SZ_WQT + SZ_WPT + SZ_QK + SZ_VT) return;

  // 1) fused prep: x->bf16 + both weight transposes (Q-cols pre-scaled by QSCALE)
  k_prep<<<3328, 256, 0, stream>>>((const float4*)x, (ushort4*)Xb,
                                   qkv_w, WqT, proj_w, WpT);
  // 2) QKV projection -> natural Q|K [m][1536] + packed V^T. 128^2 tiles, m-fastest.
  k_gemm_bt<1><<<dim3(MTOT / 128, NQKV / 128), 256, 0, stream>>>(
      Xb, WqT, MTOT, NQKV, DMODEL, nullptr, nullptr, QKn, Vt);
  // 3) fused attention -> Oattn (reuses Xb region; Xb is dead after step 2)
  k_attn<<<BB * NHEAD * 8, 512, 0, stream>>>(QKn, Vt, Xb);
  // 4) output projection + bias -> f32 out
  k_gemm_bt<0><<<dim3(MTOT / 128, DMODEL / 128), 256, 0, stream>>>(
      Xb, WpT, MTOT, DMODEL, DMODEL, out, proj_b, nullptr, nullptr);
}

// Round 14
// 167.855 us; speedup vs baseline: 1.1318x; 1.1318x over previous
//
#include <hip/hip_runtime.h>
#include <cstdint>
#include <cstddef>

typedef float f32x4 __attribute__((ext_vector_type(4)));
typedef __bf16 bf16x8 __attribute__((ext_vector_type(8)));

#define BB 16
#define SEQ 1024
#define DMODEL 768
#define NHEAD 12
#define HDIM 64
#define MTOT (BB * SEQ)
#define NQKV (3 * DMODEL)
#define NQK (2 * DMODEL)   // natural-layout Q|K row length
// 0.125 (hd^-0.5) * log2(e): QK^T then exp2 == exp(0.125 * qk)
#define QSCALE 0.18033688011112042f

static __device__ __forceinline__ unsigned short f2bf(float f) {
  unsigned int u = __builtin_bit_cast(unsigned int, f);
  u += 0x7fffu + ((u >> 16) & 1u);
  return (unsigned short)(u >> 16);
}

static __device__ __forceinline__ unsigned cvt_pk_bf16(float lo, float hi) {
  unsigned r;
  asm("v_cvt_pk_bf16_f32 %0, %1, %2" : "=v"(r) : "v"(lo), "v"(hi));
  return r;
}

static __device__ __forceinline__ float max3f(float a, float b, float c) {
  return fmaxf(fmaxf(a, b), c);   // clang fuses to v_max3_f32 (T17)
}

static __device__ __forceinline__ void gload_lds16(const void* g, void* l) {
  __builtin_amdgcn_global_load_lds((__attribute__((address_space(1))) void*)g,
                                   (__attribute__((address_space(3))) void*)l,
                                   16, 0, 0);
}

// ---- fused prep: x->bf16 cvt (blocks 0..1023) + both weight transposes ----
__global__ __launch_bounds__(256) void k_prep(
    const float4* __restrict__ x4, ushort4* __restrict__ xb4,
    const float* __restrict__ qkv_w, unsigned short* __restrict__ WqT,
    const float* __restrict__ proj_w, unsigned short* __restrict__ WpT) {
  const int blk = blockIdx.x;
  if (blk < 1024) {
    const int n4 = MTOT * DMODEL / 4;
    const int stride = 1024 * 256;
    for (int i = blk * 256 + threadIdx.x; i < n4; i += stride) {
      float4 v = x4[i];
      ushort4 o;
      o.x = f2bf(v.x); o.y = f2bf(v.y); o.z = f2bf(v.z); o.w = f2bf(v.w);
      xb4[i] = o;
    }
    return;
  }
  __shared__ float tile[32][33];
  const float* in; unsigned short* out; int C, scaleN, bx, by;
  if (blk < 1024 + 1728) {
    const int l = blk - 1024; bx = l % 72; by = l / 72;
    in = qkv_w; out = WqT; C = NQKV; scaleN = DMODEL;
  } else {
    const int l = blk - 2752; bx = l % 24; by = l / 24;
    in = proj_w; out = WpT; C = DMODEL; scaleN = 0;
  }
  const int R = DMODEL;
  const int tx = threadIdx.x & 31, ty = threadIdx.x >> 5;
  const int c0 = bx * 32, r0 = by * 32;
#pragma unroll
  for (int i = 0; i < 4; ++i)
    tile[ty + i * 8][tx] = in[(size_t)(r0 + ty + i * 8) * C + c0 + tx];
  __syncthreads();
#pragma unroll
  for (int i = 0; i < 4; ++i) {
    const int n = c0 + ty + i * 8;  // original column = output row
    float v = tile[tx][ty + i * 8];
    if (n < scaleN) v *= QSCALE;
    out[(size_t)n * R + r0 + tx] = f2bf(v);
  }
}

// ---- GEMM C[M,N] = A[M,K] * Bt[N,K]^T, bf16 in, f32 accum (R12 exact) ----
// 128x128 tile, BK=64 single-buffered (32 KB LDS), 2 barriers/K-step, 4 waves
// at 64x64 (acc 4x4 = 64 AGPR), 4 blocks/CU. T2 swizzle both-sides (rule 21).
// R13 lesson: issue-early dbuf LOSES to this at equal occupancy - TLP covers.
// MODE 0: outF = C + bias. MODE 1: natural Q|K [m][1536] + packed V^T.
template <int MODE>
__global__ __launch_bounds__(256, 4) void k_gemm_bt(
    const unsigned short* __restrict__ A, const unsigned short* __restrict__ Bt,
    int M, int N, int K,
    float* __restrict__ outF, const float* __restrict__ bias,
    unsigned short* __restrict__ QK, unsigned short* __restrict__ Vt) {
  __shared__ __align__(16) unsigned short As[128 * 64];  // 16 KB
  __shared__ __align__(16) unsigned short Bs[128 * 64];  // 16 KB
  const int tid = threadIdx.x;
  const int lane = tid & 63, wid = tid >> 6;
  const int ln15 = lane & 15, lh = lane >> 4;
  const int wr = wid >> 1, wc = wid & 1;
  const int m0 = blockIdx.x * 128, n0 = blockIdx.y * 128;
  f32x4 acc[4][4] = {};
  const int srow = lane >> 3;
  const int sblk = ((lane & 7) ^ srow) * 8;
  const int swz = (ln15 & 7) << 3;
  const int nk = K >> 6;

  for (int kt = 0; kt < nk; ++kt) {
    const int k0 = kt * 64;
#pragma unroll
    for (int c = 0; c < 4; ++c) {
      const int ch = wid * 4 + c;
      const int row = ch * 8 + srow;
      gload_lds16(A + (size_t)(m0 + row) * K + k0 + sblk, &As[ch * 512]);
      gload_lds16(Bt + (size_t)(n0 + row) * K + k0 + sblk, &Bs[ch * 512]);
    }
    __syncthreads();
#pragma unroll
    for (int kk = 0; kk < 2; ++kk) {
      const int kc = kk * 32 + lh * 8;
      bf16x8 af[4], bfv[4];
#pragma unroll
      for (int mt = 0; mt < 4; ++mt)
        af[mt] = *reinterpret_cast<const bf16x8*>(
            &As[(wr * 64 + mt * 16 + ln15) * 64 + (kc ^ swz)]);
#pragma unroll
      for (int nn = 0; nn < 4; ++nn)
        bfv[nn] = *reinterpret_cast<const bf16x8*>(
            &Bs[(wc * 64 + nn * 16 + ln15) * 64 + (kc ^ swz)]);
#pragma unroll
      for (int mt = 0; mt < 4; ++mt)
#pragma unroll
        for (int nn = 0; nn < 4; ++nn)
          acc[mt][nn] = __builtin_amdgcn_mfma_f32_16x16x32_bf16(af[mt], bfv[nn], acc[mt][nn], 0, 0, 0);
    }
    __syncthreads();
  }

#pragma unroll
  for (int mt = 0; mt < 4; ++mt) {
#pragma unroll
    for (int nn = 0; nn < 4; ++nn) {
      const int nb = n0 + wc * 64 + nn * 16;
      const int mb = m0 + wr * 64 + mt * 16 + lh * 4;
      if (MODE == 0) {
#pragma unroll
        for (int r = 0; r < 4; ++r)
          outF[(size_t)(mb + r) * N + nb + ln15] = acc[mt][nn][r] + bias[nb + ln15];
      } else if (nb < NQK) {
#pragma unroll
        for (int r = 0; r < 4; ++r)
          QK[(size_t)(mb + r) * NQK + nb + ln15] = f2bf(acc[mt][nn][r]);
      } else {
        const int rr = nb + ln15 - NQK;
        const int h = rr >> 6, d = rr & 63;
        const int b = mb >> 10, nr0 = mb & 1023;
        ushort4 u;
        u.x = f2bf(acc[mt][nn][0]); u.y = f2bf(acc[mt][nn][1]);
        u.z = f2bf(acc[mt][nn][2]); u.w = f2bf(acc[mt][nn][3]);
        *reinterpret_cast<ushort4*>(
            &Vt[(((size_t)b * NHEAD + h) * HDIM + d) * SEQ + nr0]) = u;
      }
    }
  }
}

// ---- fused flash attention, swapped-QK^T, low-VALU softmax ----
// QBLK=128, 8 waves. K/V SINGLE-buffered (34.4 KB total -> 4 blocks/CU = the
// 32-wave cap, was 3 at 50 KB) with the proven stage->sync->compute->sync
// structure (R13 lesson: TLP beats issue-early dbuf at equal occupancy).
// XCD-grouping swizzle; C-fold softmax; ones-MFMA row-sum; defer-max.
__global__ __launch_bounds__(512) void k_attn(
    const unsigned short* __restrict__ QKn, const unsigned short* __restrict__ Vt,
    unsigned short* __restrict__ O) {
  __shared__ __align__(16) unsigned short Ks[64 * 64];      // [kpos][d], swizzled
  __shared__ __align__(16) unsigned short Vs[64 * 64];      // [d][kpos], swizzled
  __shared__ __align__(16) unsigned short Ps[8][16 * 72];   // per-wave P [q][kpos]
  const int tid = threadIdx.x;
  const int lane = tid & 63, w = tid >> 6;
  const int ln15 = lane & 15, lh = lane >> 4;
  const int o = blockIdx.x;
  const int sid = (o & 7) * 192 + (o >> 3);
  const int qb = sid & 7;
  const int bhid = sid >> 3;
  const int h = bhid % NHEAD;
  const int b = bhid / NHEAD;
  const size_t bh = (size_t)(b * NHEAD + h);
  const unsigned short* Qbase = QKn + (size_t)(b * SEQ + qb * 128 + w * 16) * NQK + h * HDIM;
  const unsigned short* Kbase = QKn + (size_t)(b * SEQ) * NQK + DMODEL + h * HDIM;
  const unsigned short* Vbase = Vt + bh * HDIM * SEQ;

  const int srow = lane >> 3;
  const int sblk = ((lane & 7) ^ srow) * 8;
  const int swz = (ln15 & 7) << 3;

  bf16x8 aq[2];
#pragma unroll
  for (int ch = 0; ch < 2; ++ch)
    aq[ch] = *reinterpret_cast<const bf16x8*>(Qbase + (size_t)ln15 * NQK + ch * 32 + lh * 8);

  bf16x8 onesb;
#pragma unroll
  for (int i = 0; i < 8; ++i) onesb[i] = (__bf16)1.0f;

  f32x4 acc[4] = {};
  f32x4 accl = {};          // row-sums via ones-MFMA; elem r <-> q-row lh*4+r
  float mr = 0.f;           // running max (log2 domain)
  f32x4 cinit = {};         // splat(-mr)

  for (int kb = 0; kb < SEQ / 64; ++kb) {
    {  // stage K/V tile kb (8 chunks each; wave w takes chunk w)
      const int row = w * 8 + srow;
      gload_lds16(Kbase + (size_t)(kb * 64 + row) * NQK + sblk, &Ks[w * 512]);
      gload_lds16(Vbase + (size_t)row * SEQ + kb * 64 + sblk, &Vs[w * 512]);
    }
    __syncthreads();

    // S^T = K Q^T with C = -mr  ->  sv holds (qk - mr)
    f32x4 sv[4];
#pragma unroll
    for (int t = 0; t < 4; ++t) sv[t] = cinit;
    __builtin_amdgcn_s_setprio(1);
#pragma unroll
    for (int t = 0; t < 4; ++t) {
#pragma unroll
      for (int ch = 0; ch < 2; ++ch) {
        bf16x8 bk = *reinterpret_cast<const bf16x8*>(
            &Ks[(t * 16 + ln15) * 64 + ((ch * 32 + lh * 8) ^ swz)]);
        sv[t] = __builtin_amdgcn_mfma_f32_16x16x32_bf16(bk, aq[ch], sv[t], 0, 0, 0);
      }
    }
    __builtin_amdgcn_s_setprio(0);

    // in-lane partial max: balanced max3 tree (7 ops, depth 3)
    float pm;
    {
      const float g0 = max3f(sv[0][0], sv[0][1], sv[0][2]);
      const float g1 = max3f(sv[0][3], sv[1][0], sv[1][1]);
      const float g2 = max3f(sv[1][2], sv[1][3], sv[2][0]);
      const float g3 = max3f(sv[2][1], sv[2][2], sv[2][3]);
      const float g4 = max3f(sv[3][0], sv[3][1], sv[3][2]);
      pm = fmaxf(max3f(g0, g1, g2), max3f(g3, g4, sv[3][3]));
    }
    // defer-max: rescale only when some row grew past +8 (P bounded by 2^8)
    if (__any(pm > 8.f)) {
      float bmf = pm;
      bmf = fmaxf(bmf, __shfl_xor(bmf, 16));
      bmf = fmaxf(bmf, __shfl_xor(bmf, 32));          // full-row (qk - mr) max
      const float delta = fmaxf(bmf, 0.f);
      const float al = __builtin_amdgcn_exp2f(-delta);
#pragma unroll
      for (int t = 0; t < 4; ++t)
#pragma unroll
        for (int r = 0; r < 4; ++r) sv[t][r] -= delta;
      mr += delta;
      cinit[0] = -mr; cinit[1] = -mr; cinit[2] = -mr; cinit[3] = -mr;
      float alq[4];
#pragma unroll
      for (int r = 0; r < 4; ++r) alq[r] = __shfl(al, lh * 4 + r);
#pragma unroll
      for (int dt = 0; dt < 4; ++dt)
#pragma unroll
        for (int r = 0; r < 4; ++r) acc[dt][r] *= alq[r];
#pragma unroll
      for (int r = 0; r < 4; ++r) accl[r] *= alq[r];
    }

#pragma unroll
    for (int t = 0; t < 4; ++t)
#pragma unroll
      for (int r = 0; r < 4; ++r) sv[t][r] = __builtin_amdgcn_exp2f(sv[t][r]);

    // pack P -> LDS (A-fragment redistribution)
#pragma unroll
    for (int t = 0; t < 4; ++t) {
      uint2 u;
      u.x = cvt_pk_bf16(sv[t][0], sv[t][1]);
      u.y = cvt_pk_bf16(sv[t][2], sv[t][3]);
      *reinterpret_cast<uint2*>(&Ps[w][ln15 * 72 + t * 16 + lh * 4]) = u;
    }

    bf16x8 ap[2];
#pragma unroll
    for (int ch = 0; ch < 2; ++ch)
      ap[ch] = *reinterpret_cast<const bf16x8*>(&Ps[w][ln15 * 72 + ch * 32 + lh * 8]);
    __builtin_amdgcn_s_setprio(1);
#pragma unroll
    for (int ch = 0; ch < 2; ++ch)   // row-sum MFMA
      accl = __builtin_amdgcn_mfma_f32_16x16x32_bf16(ap[ch], onesb, accl, 0, 0, 0);
#pragma unroll
    for (int dt = 0; dt < 4; ++dt) {
#pragma unroll
      for (int ch = 0; ch < 2; ++ch) {
        bf16x8 bv = *reinterpret_cast<const bf16x8*>(
            &Vs[(dt * 16 + ln15) * 64 + ((ch * 32 + lh * 8) ^ swz)]);
        acc[dt] = __builtin_amdgcn_mfma_f32_16x16x32_bf16(ap[ch], bv, acc[dt], 0, 0, 0);
      }
    }
    __builtin_amdgcn_s_setprio(0);
    __syncthreads();
  }

  const int qrow = qb * 128 + w * 16 + lh * 4;
#pragma unroll
  for (int dt = 0; dt < 4; ++dt)
#pragma unroll
    for (int r = 0; r < 4; ++r)
      O[((size_t)b * SEQ + qrow + r) * DMODEL + h * 64 + dt * 16 + ln15] =
          f2bf(acc[dt][r] / accl[r]);
}

extern "C" void kernel_launch(void* const* d_in, const int* in_sizes, int n_in,
                              void* d_out, int out_size, void* d_ws, size_t ws_size,
                              hipStream_t stream) {
  const float* x      = (const float*)d_in[0];
  const float* qkv_w  = (const float*)d_in[1];
  const float* proj_w = (const float*)d_in[2];
  const float* proj_b = (const float*)d_in[3];
  float* out = (float*)d_out;

  char* ws = (char*)d_ws;
  const size_t SZ_XB   = (size_t)MTOT * DMODEL * 2;   // x bf16; reused as attn-out bf16
  const size_t SZ_WQT  = (size_t)NQKV * DMODEL * 2;
  const size_t SZ_WPT  = (size_t)DMODEL * DMODEL * 2;
  const size_t SZ_QK   = (size_t)MTOT * NQK * 2;      // natural Q|K [m][1536]
  const size_t SZ_VT   = (size_t)BB * NHEAD * HDIM * SEQ * 2;
  unsigned short* Xb   = (unsigned short*)ws;
  unsigned short* WqT  = (unsigned short*)(ws + SZ_XB);
  unsigned short* WpT  = (unsigned short*)(ws + SZ_XB + SZ_WQT);
  unsigned short* QKn  = (unsigned short*)(ws + SZ_XB + SZ_WQT + SZ_WPT);
  unsigned short* Vt   = (unsigned short*)(ws + SZ_XB + SZ_WQT + SZ_WPT + SZ_QK);
  if (ws_size < SZ_XB + SZ_WQT + SZ_WPT + SZ_QK + SZ_VT) return;

  // 1) fused prep: x->bf16 + both weight transposes (Q-cols pre-scaled by QSCALE)
  k_prep<<<3328, 256, 0, stream>>>((const float4*)x, (ushort4*)Xb,
                                   qkv_w, WqT, proj_w, WpT);
  // 2) QKV projection -> natural Q|K [m][1536] + packed V^T. 128^2 tiles, m-fastest.
  k_gemm_bt<1><<<dim3(MTOT / 128, NQKV / 128), 256, 0, stream>>>(
      Xb, WqT, MTOT, NQKV, DMODEL, nullptr, nullptr, QKn, Vt);
  // 3) fused attention -> Oattn (reuses Xb region; Xb is dead after step 2)
  k_attn<<<BB * NHEAD * 8, 512, 0, stream>>>(QKn, Vt, Xb);
  // 4) output projection + bias -> f32 out
  k_gemm_bt<0><<<dim3(MTOT / 128, DMODEL / 128), 256, 0, stream>>>(
      Xb, WpT, MTOT, DMODEL, DMODEL, out, proj_b, nullptr, nullptr);
}

// Round 15
// 167.679 us; speedup vs baseline: 1.1330x; 1.0011x over previous
//
#include <hip/hip_runtime.h>
#include <cstdint>
#include <cstddef>

typedef float f32x4 __attribute__((ext_vector_type(4)));
typedef __bf16 bf16x8 __attribute__((ext_vector_type(8)));

#define BB 16
#define SEQ 1024
#define DMODEL 768
#define NHEAD 12
#define HDIM 64
#define MTOT (BB * SEQ)
#define NQKV (3 * DMODEL)
#define NQK (2 * DMODEL)   // natural-layout Q|K row length
// 0.125 (hd^-0.5) * log2(e): QK^T then exp2 == exp(0.125 * qk)
#define QSCALE 0.18033688011112042f

static __device__ __forceinline__ unsigned short f2bf(float f) {
  unsigned int u = __builtin_bit_cast(unsigned int, f);
  u += 0x7fffu + ((u >> 16) & 1u);
  return (unsigned short)(u >> 16);
}

static __device__ __forceinline__ unsigned cvt_pk_bf16(float lo, float hi) {
  unsigned r;
  asm("v_cvt_pk_bf16_f32 %0, %1, %2" : "=v"(r) : "v"(lo), "v"(hi));
  return r;
}

static __device__ __forceinline__ float max3f(float a, float b, float c) {
  return fmaxf(fmaxf(a, b), c);   // clang fuses to v_max3_f32 (T17)
}

static __device__ __forceinline__ void gload_lds16(const void* g, void* l) {
  __builtin_amdgcn_global_load_lds((__attribute__((address_space(1))) void*)g,
                                   (__attribute__((address_space(3))) void*)l,
                                   16, 0, 0);
}

// ---- fused prep: x->bf16 cvt (blocks 0..1023) + both weight transposes ----
__global__ __launch_bounds__(256) void k_prep(
    const float4* __restrict__ x4, ushort4* __restrict__ xb4,
    const float* __restrict__ qkv_w, unsigned short* __restrict__ WqT,
    const float* __restrict__ proj_w, unsigned short* __restrict__ WpT) {
  const int blk = blockIdx.x;
  if (blk < 1024) {
    const int n4 = MTOT * DMODEL / 4;
    const int stride = 1024 * 256;
    for (int i = blk * 256 + threadIdx.x; i < n4; i += stride) {
      float4 v = x4[i];
      ushort4 o;
      o.x = f2bf(v.x); o.y = f2bf(v.y); o.z = f2bf(v.z); o.w = f2bf(v.w);
      xb4[i] = o;
    }
    return;
  }
  __shared__ float tile[32][33];
  const float* in; unsigned short* out; int C, scaleN, bx, by;
  if (blk < 1024 + 1728) {
    const int l = blk - 1024; bx = l % 72; by = l / 72;
    in = qkv_w; out = WqT; C = NQKV; scaleN = DMODEL;
  } else {
    const int l = blk - 2752; bx = l % 24; by = l / 24;
    in = proj_w; out = WpT; C = DMODEL; scaleN = 0;
  }
  const int R = DMODEL;
  const int tx = threadIdx.x & 31, ty = threadIdx.x >> 5;
  const int c0 = bx * 32, r0 = by * 32;
#pragma unroll
  for (int i = 0; i < 4; ++i)
    tile[ty + i * 8][tx] = in[(size_t)(r0 + ty + i * 8) * C + c0 + tx];
  __syncthreads();
#pragma unroll
  for (int i = 0; i < 4; ++i) {
    const int n = c0 + ty + i * 8;  // original column = output row
    float v = tile[tx][ty + i * 8];
    if (n < scaleN) v *= QSCALE;
    out[(size_t)n * R + r0 + tx] = f2bf(v);
  }
}

// ---- GEMM C[M,N] = A[M,K] * Bt[N,K]^T, bf16 in, f32 accum ----
// K-loop/epilogue = R12/R14 exact. NEW: XCD-supertiled flat grid. Each XCD owns
// 16 consecutive m-blocks (2048-row A-supertile = 3 MB, fits its private 4 MB
// L2) and iterates n-panels n-outer/m-inner (B-panel 192 KB resident). Cuts
// A's L3->L2 re-stream from nNB x 24 MB to ~1x. Relies on o%8=XCD modularity
// (validated by R9's attn FETCH collapse). Requires M/128 % 8 == 0 (128 ok).
// MODE 0: outF = C + bias. MODE 1: natural Q|K [m][1536] + packed V^T.
template <int MODE>
__global__ __launch_bounds__(256, 4) void k_gemm_bt(
    const unsigned short* __restrict__ A, const unsigned short* __restrict__ Bt,
    int M, int N, int K,
    float* __restrict__ outF, const float* __restrict__ bias,
    unsigned short* __restrict__ QK, unsigned short* __restrict__ Vt) {
  __shared__ __align__(16) unsigned short As[128 * 64];  // 16 KB
  __shared__ __align__(16) unsigned short Bs[128 * 64];  // 16 KB
  const int tid = threadIdx.x;
  const int lane = tid & 63, wid = tid >> 6;
  const int ln15 = lane & 15, lh = lane >> 4;
  const int wr = wid >> 1, wc = wid & 1;
  // XCD-supertiled mapping: xcd = o&7 owns m-blocks [xcd*16, xcd*16+16)
  const int o = blockIdx.x;
  const int xcd = o & 7, lsid = o >> 3;
  const int n0 = (lsid >> 4) * 128;
  const int m0 = ((xcd << 4) + (lsid & 15)) * 128;
  f32x4 acc[4][4] = {};
  const int srow = lane >> 3;
  const int sblk = ((lane & 7) ^ srow) * 8;
  const int swz = (ln15 & 7) << 3;
  const int nk = K >> 6;

  for (int kt = 0; kt < nk; ++kt) {
    const int k0 = kt * 64;
#pragma unroll
    for (int c = 0; c < 4; ++c) {
      const int ch = wid * 4 + c;
      const int row = ch * 8 + srow;
      gload_lds16(A + (size_t)(m0 + row) * K + k0 + sblk, &As[ch * 512]);
      gload_lds16(Bt + (size_t)(n0 + row) * K + k0 + sblk, &Bs[ch * 512]);
    }
    __syncthreads();
#pragma unroll
    for (int kk = 0; kk < 2; ++kk) {
      const int kc = kk * 32 + lh * 8;
      bf16x8 af[4], bfv[4];
#pragma unroll
      for (int mt = 0; mt < 4; ++mt)
        af[mt] = *reinterpret_cast<const bf16x8*>(
            &As[(wr * 64 + mt * 16 + ln15) * 64 + (kc ^ swz)]);
#pragma unroll
      for (int nn = 0; nn < 4; ++nn)
        bfv[nn] = *reinterpret_cast<const bf16x8*>(
            &Bs[(wc * 64 + nn * 16 + ln15) * 64 + (kc ^ swz)]);
#pragma unroll
      for (int mt = 0; mt < 4; ++mt)
#pragma unroll
        for (int nn = 0; nn < 4; ++nn)
          acc[mt][nn] = __builtin_amdgcn_mfma_f32_16x16x32_bf16(af[mt], bfv[nn], acc[mt][nn], 0, 0, 0);
    }
    __syncthreads();
  }

#pragma unroll
  for (int mt = 0; mt < 4; ++mt) {
#pragma unroll
    for (int nn = 0; nn < 4; ++nn) {
      const int nb = n0 + wc * 64 + nn * 16;
      const int mb = m0 + wr * 64 + mt * 16 + lh * 4;
      if (MODE == 0) {
#pragma unroll
        for (int r = 0; r < 4; ++r)
          outF[(size_t)(mb + r) * N + nb + ln15] = acc[mt][nn][r] + bias[nb + ln15];
      } else if (nb < NQK) {
#pragma unroll
        for (int r = 0; r < 4; ++r)
          QK[(size_t)(mb + r) * NQK + nb + ln15] = f2bf(acc[mt][nn][r]);
      } else {
        const int rr = nb + ln15 - NQK;
        const int h = rr >> 6, d = rr & 63;
        const int b = mb >> 10, nr0 = mb & 1023;
        ushort4 u;
        u.x = f2bf(acc[mt][nn][0]); u.y = f2bf(acc[mt][nn][1]);
        u.z = f2bf(acc[mt][nn][2]); u.w = f2bf(acc[mt][nn][3]);
        *reinterpret_cast<ushort4*>(
            &Vt[(((size_t)b * NHEAD + h) * HDIM + d) * SEQ + nr0]) = u;
      }
    }
  }
}

// ---- fused flash attention, swapped-QK^T, low-VALU softmax (R14 exact) ----
__global__ __launch_bounds__(512) void k_attn(
    const unsigned short* __restrict__ QKn, const unsigned short* __restrict__ Vt,
    unsigned short* __restrict__ O) {
  __shared__ __align__(16) unsigned short Ks[64 * 64];      // [kpos][d], swizzled
  __shared__ __align__(16) unsigned short Vs[64 * 64];      // [d][kpos], swizzled
  __shared__ __align__(16) unsigned short Ps[8][16 * 72];   // per-wave P [q][kpos]
  const int tid = threadIdx.x;
  const int lane = tid & 63, w = tid >> 6;
  const int ln15 = lane & 15, lh = lane >> 4;
  const int o = blockIdx.x;
  const int sid = (o & 7) * 192 + (o >> 3);
  const int qb = sid & 7;
  const int bhid = sid >> 3;
  const int h = bhid % NHEAD;
  const int b = bhid / NHEAD;
  const size_t bh = (size_t)(b * NHEAD + h);
  const unsigned short* Qbase = QKn + (size_t)(b * SEQ + qb * 128 + w * 16) * NQK + h * HDIM;
  const unsigned short* Kbase = QKn + (size_t)(b * SEQ) * NQK + DMODEL + h * HDIM;
  const unsigned short* Vbase = Vt + bh * HDIM * SEQ;

  const int srow = lane >> 3;
  const int sblk = ((lane & 7) ^ srow) * 8;
  const int swz = (ln15 & 7) << 3;

  bf16x8 aq[2];
#pragma unroll
  for (int ch = 0; ch < 2; ++ch)
    aq[ch] = *reinterpret_cast<const bf16x8*>(Qbase + (size_t)ln15 * NQK + ch * 32 + lh * 8);

  bf16x8 onesb;
#pragma unroll
  for (int i = 0; i < 8; ++i) onesb[i] = (__bf16)1.0f;

  f32x4 acc[4] = {};
  f32x4 accl = {};          // row-sums via ones-MFMA; elem r <-> q-row lh*4+r
  float mr = 0.f;           // running max (log2 domain)
  f32x4 cinit = {};         // splat(-mr)

  for (int kb = 0; kb < SEQ / 64; ++kb) {
    {  // stage K/V tile kb (8 chunks each; wave w takes chunk w)
      const int row = w * 8 + srow;
      gload_lds16(Kbase + (size_t)(kb * 64 + row) * NQK + sblk, &Ks[w * 512]);
      gload_lds16(Vbase + (size_t)row * SEQ + kb * 64 + sblk, &Vs[w * 512]);
    }
    __syncthreads();

    // S^T = K Q^T with C = -mr  ->  sv holds (qk - mr)
    f32x4 sv[4];
#pragma unroll
    for (int t = 0; t < 4; ++t) sv[t] = cinit;
    __builtin_amdgcn_s_setprio(1);
#pragma unroll
    for (int t = 0; t < 4; ++t) {
#pragma unroll
      for (int ch = 0; ch < 2; ++ch) {
        bf16x8 bk = *reinterpret_cast<const bf16x8*>(
            &Ks[(t * 16 + ln15) * 64 + ((ch * 32 + lh * 8) ^ swz)]);
        sv[t] = __builtin_amdgcn_mfma_f32_16x16x32_bf16(bk, aq[ch], sv[t], 0, 0, 0);
      }
    }
    __builtin_amdgcn_s_setprio(0);

    // in-lane partial max: balanced max3 tree (7 ops, depth 3)
    float pm;
    {
      const float g0 = max3f(sv[0][0], sv[0][1], sv[0][2]);
      const float g1 = max3f(sv[0][3], sv[1][0], sv[1][1]);
      const float g2 = max3f(sv[1][2], sv[1][3], sv[2][0]);
      const float g3 = max3f(sv[2][1], sv[2][2], sv[2][3]);
      const float g4 = max3f(sv[3][0], sv[3][1], sv[3][2]);
      pm = fmaxf(max3f(g0, g1, g2), max3f(g3, g4, sv[3][3]));
    }
    // defer-max: rescale only when some row grew past +8 (P bounded by 2^8)
    if (__any(pm > 8.f)) {
      float bmf = pm;
      bmf = fmaxf(bmf, __shfl_xor(bmf, 16));
      bmf = fmaxf(bmf, __shfl_xor(bmf, 32));          // full-row (qk - mr) max
      const float delta = fmaxf(bmf, 0.f);
      const float al = __builtin_amdgcn_exp2f(-delta);
#pragma unroll
      for (int t = 0; t < 4; ++t)
#pragma unroll
        for (int r = 0; r < 4; ++r) sv[t][r] -= delta;
      mr += delta;
      cinit[0] = -mr; cinit[1] = -mr; cinit[2] = -mr; cinit[3] = -mr;
      float alq[4];
#pragma unroll
      for (int r = 0; r < 4; ++r) alq[r] = __shfl(al, lh * 4 + r);
#pragma unroll
      for (int dt = 0; dt < 4; ++dt)
#pragma unroll
        for (int r = 0; r < 4; ++r) acc[dt][r] *= alq[r];
#pragma unroll
      for (int r = 0; r < 4; ++r) accl[r] *= alq[r];
    }

#pragma unroll
    for (int t = 0; t < 4; ++t)
#pragma unroll
      for (int r = 0; r < 4; ++r) sv[t][r] = __builtin_amdgcn_exp2f(sv[t][r]);

    // pack P -> LDS (A-fragment redistribution)
#pragma unroll
    for (int t = 0; t < 4; ++t) {
      uint2 u;
      u.x = cvt_pk_bf16(sv[t][0], sv[t][1]);
      u.y = cvt_pk_bf16(sv[t][2], sv[t][3]);
      *reinterpret_cast<uint2*>(&Ps[w][ln15 * 72 + t * 16 + lh * 4]) = u;
    }

    bf16x8 ap[2];
#pragma unroll
    for (int ch = 0; ch < 2; ++ch)
      ap[ch] = *reinterpret_cast<const bf16x8*>(&Ps[w][ln15 * 72 + ch * 32 + lh * 8]);
    __builtin_amdgcn_s_setprio(1);
#pragma unroll
    for (int ch = 0; ch < 2; ++ch)   // row-sum MFMA
      accl = __builtin_amdgcn_mfma_f32_16x16x32_bf16(ap[ch], onesb, accl, 0, 0, 0);
#pragma unroll
    for (int dt = 0; dt < 4; ++dt) {
#pragma unroll
      for (int ch = 0; ch < 2; ++ch) {
        bf16x8 bv = *reinterpret_cast<const bf16x8*>(
            &Vs[(dt * 16 + ln15) * 64 + ((ch * 32 + lh * 8) ^ swz)]);
        acc[dt] = __builtin_amdgcn_mfma_f32_16x16x32_bf16(ap[ch], bv, acc[dt], 0, 0, 0);
      }
    }
    __builtin_amdgcn_s_setprio(0);
    __syncthreads();
  }

  const int qrow = qb * 128 + w * 16 + lh * 4;
#pragma unroll
  for (int dt = 0; dt < 4; ++dt)
#pragma unroll
    for (int r = 0; r < 4; ++r)
      O[((size_t)b * SEQ + qrow + r) * DMODEL + h * 64 + dt * 16 + ln15] =
          f2bf(acc[dt][r] / accl[r]);
}

extern "C" void kernel_launch(void* const* d_in, const int* in_sizes, int n_in,
                              void* d_out, int out_size, void* d_ws, size_t ws_size,
                              hipStream_t stream) {
  const float* x      = (const float*)d_in[0];
  const float* qkv_w  = (const float*)d_in[1];
  const float* proj_w = (const float*)d_in[2];
  const float* proj_b = (const float*)d_in[3];
  float* out = (float*)d_out;

  char* ws = (char*)d_ws;
  const size_t SZ_XB   = (size_t)MTOT * DMODEL * 2;   // x bf16; reused as attn-out bf16
  const size_t SZ_WQT  = (size_t)NQKV * DMODEL * 2;
  const size_t SZ_WPT  = (size_t)DMODEL * DMODEL * 2;
  const size_t SZ_QK   = (size_t)MTOT * NQK * 2;      // natural Q|K [m][1536]
  const size_t SZ_VT   = (size_t)BB * NHEAD * HDIM * SEQ * 2;
  unsigned short* Xb   = (unsigned short*)ws;
  unsigned short* WqT  = (unsigned short*)(ws + SZ_XB);
  unsigned short* WpT  = (unsigned short*)(ws + SZ_XB + SZ_WQT);
  unsigned short* QKn  = (unsigned short*)(ws + SZ_XB + SZ_WQT + SZ_WPT);
  unsigned short* Vt   = (unsigned short*)(ws + SZ_XB + SZ_WQT + SZ_WPT + SZ_QK);
  if (ws_size < SZ_XB + SZ_WQT + SZ_WPT + SZ_QK + SZ_VT) return;

  // 1) fused prep: x->bf16 + both weight transposes (Q-cols pre-scaled by QSCALE)
  k_prep<<<3328, 256, 0, stream>>>((const float4*)x, (ushort4*)Xb,
                                   qkv_w, WqT, proj_w, WpT);
  // 2) QKV projection -> natural Q|K [m][1536] + packed V^T. XCD-supertiled grid.
  k_gemm_bt<1><<<(MTOT / 128) * (NQKV / 128), 256, 0, stream>>>(
      Xb, WqT, MTOT, NQKV, DMODEL, nullptr, nullptr, QKn, Vt);
  // 3) fused attention -> Oattn (reuses Xb region; Xb is dead after step 2)
  k_attn<<<BB * NHEAD * 8, 512, 0, stream>>>(QKn, Vt, Xb);
  // 4) output projection + bias -> f32 out. XCD-supertiled grid.
  k_gemm_bt<0><<<(MTOT / 128) * (DMODEL / 128), 256, 0, stream>>>(
      Xb, WpT, MTOT, DMODEL, DMODEL, out, proj_b, nullptr, nullptr);
}